// Round 20
// baseline (20.185 us; speedup 1.0000x reference)
//
#include <hip/hip_runtime.h>
#include <hip/hip_bf16.h>

// Problem dims (fixed): n=128, d=256, ic=16, oc=16, r=10
// x:   [n, d, ic, r]  f32; w: [d, ic, oc, r] f32; out: [n, d, oc, r] f32
// out[n,d,oc,r] = log( sum_ic exp(x)*exp(w) ) - log( sum_ic exp(w) )
//
// v20: wave-autonomous MFMA. Every prior variant ran big barrier-synced
// blocks with grid == residency: all waves per CU in lockstep phases ->
// each phase's latency fully exposed (v17: nothing >42% busy). Here:
// block = ONE wave = (d, 8 n); grid 4096 > resident ~3072 -> backfill;
// ZERO barriers (es wave-private, lgkmcnt-only visibility); B-fragments
// + lcs pre-baked by prep (v15-verified) and loaded to registers; A rows
// 8..15 and slots 16..31 zero (v16/v18-verified K/M-pad); 10 MFMAs; short
// chains. Waves self-stagger via load arrival -> loads overlap compute
// across waves without any scheduling structure.

typedef __attribute__((ext_vector_type(8))) short bf16x8;
typedef __attribute__((ext_vector_type(4))) float f32x4;

#define LCS_OFF 1310720   // bytes: wfrag = 256 d * 10 r * 512 B

__device__ __forceinline__ unsigned short f2bf(float v) {
    unsigned u = __float_as_uint(v);
    u += 0x7FFF + ((u >> 16) & 1);
    return (unsigned short)(u >> 16);
}

// ---------------- prep: wfrag[(d*10+r)*128 + lane*4 + wsel] + lcs -----------
// (verbatim from v15 — correctness-verified in v15 and v16 runs)
__global__ __launch_bounds__(256) void prep_kernel(const float* __restrict__ w,
                                                   void* __restrict__ ws) {
    __shared__ float lexp[2560];         // [(ic*16+oc)*10 + r]
    const int d   = blockIdx.x;
    const int tid = threadIdx.x;         // = ic*16 + oc
    const int ic  = tid >> 4, oc = tid & 15;

    const float* wp = w + d * 2560 + ic * 160 + oc * 10;
#pragma unroll
    for (int k = 0; k < 5; ++k) {
        float2 v = *reinterpret_cast<const float2*>(wp + 2 * k);
        lexp[tid * 10 + 2 * k]     = __expf(v.x);
        lexp[tid * 10 + 2 * k + 1] = __expf(v.y);
    }
    __syncthreads();

    if (tid < 160) {
        const int o2 = tid / 10, rr = tid - (tid / 10) * 10;
        float s = 0.f;
#pragma unroll
        for (int i2 = 0; i2 < 16; ++i2) s += lexp[(i2 * 16 + o2) * 10 + rr];
        float* lcs = reinterpret_cast<float*>(reinterpret_cast<char*>(ws) + LCS_OFF);
        lcs[d * 160 + tid] = __logf(s);
    }

    unsigned* wf = reinterpret_cast<unsigned*>(ws);
    const int idx    = tid & 127;
    const int lane32 = idx >> 2;
    const int wsel   = idx & 3;
    const int kg     = lane32 >> 4;
    const int oc2    = lane32 & 15;
    const int s0     = kg * 8 + wsel * 2;
#pragma unroll
    for (int rr2 = 0; rr2 < 5; ++rr2) {
        const int r = rr2 * 2 + (tid >> 7);
        const unsigned lo = f2bf(lexp[(s0 * 16 + oc2) * 10 + r]);
        const unsigned hi = f2bf(lexp[((s0 + 1) * 16 + oc2) * 10 + r]);
        wf[(d * 10 + r) * 128 + idx] = lo | (hi << 16);
    }
}

// ---------------- main: 4096 blocks x 64 thr (1 wave), zero barriers --------
__global__ __launch_bounds__(64, 3) void main_kernel(const float* __restrict__ x,
                                                     const void* __restrict__ ws,
                                                     float* __restrict__ out) {
    __shared__ __align__(16) unsigned short es[8 * 168];   // 2.7 KB, wave-private

    const int tid = threadIdx.x;         // 0..63
    const int d   = blockIdx.x & 255;    // same-d blocks -> same XCD (256%8==0)
    const int n0  = (blockIdx.x >> 8) << 3;   // 16 chunks of 8 n
    const int lm  = tid & 15;            // oc / C col
    const int kg  = tid >> 4;            // k-group / C row-quad

    // ---- issue x loads FIRST (HBM, slowest), then B-frags + lcs (L2) -------
    const int row  = tid >> 3;           // 0..7  (n-local)
    const int part = tid & 7;            // 20-float segment of the 640B row
    const float* xg = x + ((n0 + row) * 256 + d) * 160 + part * 20;
    float4 xv[5];
#pragma unroll
    for (int k = 0; k < 5; ++k) xv[k] = *reinterpret_cast<const float4*>(xg + 4 * k);

    const bf16x8 zero8 = {0, 0, 0, 0, 0, 0, 0, 0};
    bf16x8 bfr[10];
    const unsigned* wf = reinterpret_cast<const unsigned*>(ws);
#pragma unroll
    for (int r = 0; r < 10; ++r)
        bfr[r] = (tid < 32)
            ? *reinterpret_cast<const bf16x8*>(&wf[(d * 10 + r) * 128 + tid * 4])
            : zero8;                      // B slots 16..31 = K-pad (verified)

    float lc[10];
    {
        const float* lcsp = reinterpret_cast<const float*>(
            reinterpret_cast<const char*>(ws) + LCS_OFF) + d * 160 + lm * 10;
#pragma unroll
        for (int k = 0; k < 5; ++k) {
            float2 v = *reinterpret_cast<const float2*>(lcsp + 2 * k);
            lc[2 * k] = v.x; lc[2 * k + 1] = v.y;
        }
    }

    // ---- stage exp(x) into wave-private es[row][r*16+ic] --------------------
    {
        const float* xf = reinterpret_cast<const float*>(xv);
#pragma unroll
        for (int k = 0; k < 20; ++k) {
            const int ic = part * 2 + (k >= 10 ? 1 : 0);
            const int r  = k % 10;
            es[row * 168 + r * 16 + ic] = f2bf(__expf(xf[k]));
        }
    }
    asm volatile("s_waitcnt lgkmcnt(0)" ::: "memory");  // own-wave writes done
    __builtin_amdgcn_sched_barrier(0);                  // rule #18 fence

    // ---- 10 MFMAs: A rows 8..15 zero (M-pad), slots 16..31 zero (K-pad) ----
    const f32x4 zeroc = {0.f, 0.f, 0.f, 0.f};
    f32x4 acc[10];
#pragma unroll
    for (int r = 0; r < 10; ++r) {
        bf16x8 a = (kg < 2 && lm < 8)
            ? *reinterpret_cast<const bf16x8*>(&es[lm * 168 + r * 16 + kg * 8])
            : zero8;
        acc[r] = __builtin_amdgcn_mfma_f32_16x16x32_bf16(a, bfr[r], zeroc, 0, 0, 0);
    }

    // ---- epilogue: C col=lm, row=kg*4+j (m89-verified); rows 0..7 real -----
    if (kg < 2) {
#pragma unroll
        for (int j = 0; j < 4; ++j) {
            const int n = n0 + kg * 4 + j;
            float* og = out + (n * 256 + d) * 160 + lm * 10;
#pragma unroll
            for (int h = 0; h < 5; ++h) {
                float2 o;
                o.x = __logf(acc[2 * h][j])     - lc[2 * h];
                o.y = __logf(acc[2 * h + 1][j]) - lc[2 * h + 1];
                *reinterpret_cast<float2*>(og + 2 * h) = o;
            }
        }
    }
}

extern "C" void kernel_launch(void* const* d_in, const int* in_sizes, int n_in,
                              void* d_out, int out_size, void* d_ws, size_t ws_size,
                              hipStream_t stream) {
    const float* x = (const float*)d_in[0];
    const float* w = (const float*)d_in[1];
    float* out = (float*)d_out;

    prep_kernel<<<256, 256, 0, stream>>>(w, d_ws);
    // 4096 blocks: d = bid&255 (XCD-local per d), n-chunk = bid>>8 (16 x 8n)
    main_kernel<<<4096, 64, 0, stream>>>(x, d_ws, out);
}

// Round 21
// 16.386 us; speedup vs baseline: 1.2318x; 1.2318x over previous
//
#include <hip/hip_runtime.h>
#include <hip/hip_bf16.h>

// Problem dims (fixed): n=128, d=256, ic=16, oc=16, r=10
// x:   [n, d, ic, r]  f32; w: [d, ic, oc, r] f32; out: [n, d, oc, r] f32
// out[n,d,oc,r] = log( sum_ic exp(x)*exp(w) ) - log( sum_ic exp(w) )
//
// FINAL (v21 = v14 verbatim, session best 16.65us): MFMA with K zero-padded
// 16->32 (both operands slot-indexed -> HW k-permutation cancels; m89
// C-layout verified), block = (d, 64n), 256 threads, 54 KB LDS ->
// 2 blocks/CU, packed b64 staging writes.
//
// Session evidence for why this is the plateau: 9 structural theories
// falsified (occupancy 2x, LDS width/count, pipeline depth, barrier
// vmcnt-drain, barrier-free, store density, DRAM run-length, wave-
// autonomy) — three disparate structures all land 16.6-17.0us. v17
// diagnostic: warm steady-state rep = 8.4us with no pipe >42% busy;
// harness dur == dispatch dur. Residual ~8us = launch ramp + cold-cache
// transient at 45 MB working set, invariant to kernel structure.

typedef __attribute__((ext_vector_type(8))) short bf16x8;
typedef __attribute__((ext_vector_type(4))) float f32x4;

__device__ __forceinline__ unsigned short f2bf(float v) {
    unsigned u = __float_as_uint(v);
    u += 0x7FFF + ((u >> 16) & 1);
    return (unsigned short)(u >> 16);
}

__global__ __launch_bounds__(256, 2) void fused_mfma_kernel(const float* __restrict__ x,
                                                            const float* __restrict__ w,
                                                            float* __restrict__ out) {
    // es[n=64][r*32+slot] bf16, row stride 328 shorts (656B -> banks shift 4/row)
    __shared__ __align__(16) unsigned short es[64 * 328];    // 42.0 KB
    // ws[r=10][oc*40+slot] bf16
    __shared__ __align__(16) unsigned short ws_[10 * 640];   // 12.8 KB
    __shared__ float lcs[160];                                // lcs[oc*10+r]

    const int tid = threadIdx.x;
    const int d   = blockIdx.x & 255;
    const int nb  = (blockIdx.x >> 8) << 6;      // 0 or 64

    // ---- phase 1: stage x (packed b64 writes) + w + pad zeros ---------------
    {
        const int n_l = tid >> 2;                // 0..63
        const int seg = tid & 3;                 // 0..3 (40 dwords each)
        const float* xg = x + ((nb + n_l) * 256 + d) * 160 + seg * 40;
        float4 xv[10];
#pragma unroll
        for (int k = 0; k < 10; ++k) xv[k] = *reinterpret_cast<const float4*>(xg + 4 * k);

        const float* wgp = w + d * 2560 + tid * 10;
        float wv[10];
#pragma unroll
        for (int k = 0; k < 5; ++k) {
            float2 v = *reinterpret_cast<const float2*>(wgp + 2 * k);
            wv[2 * k] = v.x; wv[2 * k + 1] = v.y;
        }

        const float* xf = reinterpret_cast<const float*>(xv);
        // per r: pack bf16 of exp(xf[r]), exp(xf[10+r]), exp(xf[20+r]), exp(xf[30+r])
        //        -> es[n_l][r*32 + 4*seg .. +3]; zeros -> slots 16+4*seg .. +3
#pragma unroll
        for (int r = 0; r < 10; ++r) {
            unsigned short s0 = f2bf(__expf(xf[r]));
            unsigned short s1 = f2bf(__expf(xf[10 + r]));
            unsigned short s2 = f2bf(__expf(xf[20 + r]));
            unsigned short s3 = f2bf(__expf(xf[30 + r]));
            const unsigned lo = (unsigned)s0 | ((unsigned)s1 << 16);
            const unsigned hi = (unsigned)s2 | ((unsigned)s3 << 16);
            unsigned* dst = reinterpret_cast<unsigned*>(&es[n_l * 328 + r * 32 + 4 * seg]);
            *reinterpret_cast<uint2*>(dst) = make_uint2(lo, hi);
            unsigned* pad = reinterpret_cast<unsigned*>(&es[n_l * 328 + r * 32 + 16 + 4 * seg]);
            *reinterpret_cast<uint2*>(pad) = make_uint2(0u, 0u);
        }
        // w: 10 scattered b16 writes
#pragma unroll
        for (int k = 0; k < 10; ++k) {
            const int off = tid * 10 + k;        // = ic*160 + oc*10 + r
            const int ic  = off / 160;
            const int rem = off - ic * 160;
            const int oc  = rem / 10;
            const int r   = rem - oc * 10;
            ws_[r * 640 + oc * 40 + ic] = f2bf(__expf(wv[k]));
        }
        // ws pad slots 16..31 for all 160 (r,oc)
        if (tid < 160) {
            const int r = tid >> 4, oc = tid & 15;
            uint4* p = reinterpret_cast<uint4*>(&ws_[r * 640 + oc * 40 + 16]);
            const uint4 z = make_uint4(0u, 0u, 0u, 0u);
            p[0] = z; p[1] = z;
        }
    }
    __syncthreads();

    // ---- phase 2: lcs (160 thr) + MFMAs (all 4 waves) ------------------------
    if (tid < 160) {
        const int oc = tid / 10, r = tid - (tid / 10) * 10;
        const unsigned short* p = &ws_[r * 640 + oc * 40];
        float s = 0.f;
#pragma unroll
        for (int ic = 0; ic < 16; ++ic)
            s += __uint_as_float(((unsigned)p[ic]) << 16);
        lcs[oc * 10 + r] = __logf(s);
    }

    const int mt = tid >> 6;             // wave id = m-tile 0..3 (n0 = 16*mt)
    const int l  = tid & 63;
    const int lm = l & 15;               // A row within tile / B col (oc)
    const int kg = l >> 4;               // k-slot group 0..3

    const int abase = (mt * 16 + lm) * 328 + kg * 8;
    const int bbase = lm * 40 + kg * 8;

    f32x4 acc[10];
    const f32x4 zero = {0.f, 0.f, 0.f, 0.f};
#pragma unroll
    for (int r = 0; r < 10; ++r) {
        bf16x8 a = *reinterpret_cast<const bf16x8*>(&es[abase + r * 32]);
        bf16x8 b = *reinterpret_cast<const bf16x8*>(&ws_[r * 640 + bbase]);
        acc[r] = __builtin_amdgcn_mfma_f32_16x16x32_bf16(a, b, zero, 0, 0, 0);
    }
    __syncthreads();   // lcs visible

    // ---- phase 3: epilogue, direct coalesced stores --------------------------
    // C layout (m89, v13-verified): col = lane&15 (=oc), row = kg*4 + j
    float lc[10];
#pragma unroll
    for (int r = 0; r < 10; ++r) lc[r] = lcs[lm * 10 + r];

#pragma unroll
    for (int j = 0; j < 4; ++j) {
        const int n = mt * 16 + kg * 4 + j;
        float* og = out + ((nb + n) * 256 + d) * 160 + lm * 10;
#pragma unroll
        for (int h = 0; h < 5; ++h) {
            float2 o;
            o.x = __logf(acc[2 * h][j])     - lc[2 * h];
            o.y = __logf(acc[2 * h + 1][j]) - lc[2 * h + 1];
            *reinterpret_cast<float2*>(og + 2 * h) = o;
        }
    }
}

extern "C" void kernel_launch(void* const* d_in, const int* in_sizes, int n_in,
                              void* d_out, int out_size, void* d_ws, size_t ws_size,
                              hipStream_t stream) {
    const float* x = (const float*)d_in[0];
    const float* w = (const float*)d_in[1];
    float* out = (float*)d_out;

    // 512 blocks: d = bid&255, n-half = bid>>8; 2 blocks/CU
    fused_mfma_kernel<<<512, 256, 0, stream>>>(x, w, out);
}